// Round 5
// baseline (142.848 us; speedup 1.0000x reference)
//
#include <hip/hip_runtime.h>
#include <math.h>

typedef unsigned int u32;
typedef unsigned long long u64;

#define N_ELEM 131072
#define NBIN 16384         // 14-bit key-space bins
#define BSH 18             // key >> 18 -> bin
#define CAP 4096           // candidate capacity per array (typ. ~25 used)
#define SEGCAP 2048        // LDS segment-table capacity in rankmom
#define SCAN_CAP 64        // max bins scanned upward in successor proof
#define GMARG 0.0999       // conservative gap margin (< 0.1*(1-1e-9))
#define NBLK 64            // data blocks per array (2048 elems each)
#define RM_BLK 128         // rankmom blocks

// ascending-sortable key: monotone bijection f32 -> u32
__device__ __forceinline__ u32 kasc(float x) {
  u32 u = __float_as_uint(x);
  return (u & 0x80000000u) ? ~u : (u | 0x80000000u);
}
__device__ __forceinline__ float kasc2f(u32 t) {
  return __uint_as_float((t & 0x80000000u) ? (t ^ 0x80000000u) : ~t);
}

// ---------------- init scratch (ws is poisoned, not re-poisoned between replays) ----
__global__ __launch_bounds__(256) void k_zero(u32* binCnt, u32* binMinK, u32* binMaxK,
                                              u32* candCnt) {
  int i = blockIdx.x * 256 + threadIdx.x;  // grid 128 -> 32768 = 2*NBIN
  binCnt[i] = 0u;
  binMinK[i] = 0xFFFFFFFFu;
  binMaxK[i] = 0u;
  if (i < 2) candCnt[i] = 0u;
}

// ---------------- binned occupancy + exact per-bin min/max keys ----------------
__global__ __launch_bounds__(256) void k_hist(const float* in0, const float* in1,
                                              u32* binCnt, u32* binMinK, u32* binMaxK) {
  int arr = blockIdx.y, b = blockIdx.x, t = threadIdx.x;
  __shared__ u32 lc[NBIN];  // 64 KB
  for (int k = t; k < NBIN; k += 256) lc[k] = 0u;
  __syncthreads();
  const float* p = arr ? in1 : in0;
  const float4* p4 = (const float4*)(p + b * 2048);
  float4 va = p4[t], vb = p4[t + 256];
  float xs[8] = {va.x, va.y, va.z, va.w, vb.x, vb.y, vb.z, vb.w};
  u32* bmn = binMinK + arr * NBIN;
  u32* bmx = binMaxK + arr * NBIN;
#pragma unroll
  for (int e = 0; e < 8; e++) {
    u32 k = kasc(xs[e]);
    u32 bin = k >> BSH;
    atomicAdd(&lc[bin], 1u);
    atomicMin(&bmn[bin], k);   // order-independent -> deterministic
    atomicMax(&bmx[bin], k);
  }
  __syncthreads();
  u32* bc = binCnt + arr * NBIN;
  for (int k = t; k < NBIN; k += 256)
    if (lc[k]) atomicAdd(&bc[k], lc[k]);
}

// ---------------- candidate detection ----------------
// Flag x unless we can PROVE an element exists in (x, x+GMARG] (then the sorted
// gap above x's run is <= GMARG < reg -> x cannot be a hull vertex; rigorous
// necessary condition: vertex at p => y_{p-1} > y_p => gap > reg).
// Proof sources (exact values): own-bin maxKey, or first nonempty higher bin's
// minKey. Over-inclusion is safe: every flagged value v yields a valid diagram
// point (p,C[p]) with p = #{> v}; the exact f64 hull discards non-vertices.
__global__ __launch_bounds__(256) void k_flag(const float* in0, const float* in1,
                                              const u32* binCnt, const u32* binMinK,
                                              const u32* binMaxK, u32* candCnt,
                                              float* candVal) {
  int arr = blockIdx.y, b = blockIdx.x, t = threadIdx.x;
  const float* p = arr ? in1 : in0;
  const u32* bc = binCnt + arr * NBIN;
  const u32* bmn = binMinK + arr * NBIN;
  const u32* bmx = binMaxK + arr * NBIN;
  if (b == 0 && t == 0) {  // right-endpoint sentinel: p = N (counts everything)
    u32 s = atomicAdd(&candCnt[arr], 1u);
    if (s < CAP) candVal[arr * CAP + s] = -INFINITY;
  }
  const float4* p4 = (const float4*)(p + b * 2048);
  float4 va = p4[t], vb = p4[t + 256];
  float xs[8] = {va.x, va.y, va.z, va.w, vb.x, vb.y, vb.z, vb.w};
  for (int e = 0; e < 8; e++) {
    float x = xs[e];
    double xd = (double)x;
    u32 k = kasc(x);
    u32 bn = k >> BSH;
    bool proven = false, decided = false;
    u32 mx = bmx[bn];
    if (mx > k) {  // someone strictly above me in my own bin (exact value known)
      proven = ((double)kasc2f(mx) - xd <= GMARG);
      decided = true;  // if not proven: higher bins are all > val(mx) > x+G -> flag
    }
    if (!decided) {
      for (int it = 0; it < SCAN_CAP; it++) {
        bn++;
        if (bn >= NBIN) break;  // nothing above -> flag (this is the max elem, p=0)
        double lb = (double)kasc2f(bn << BSH);  // bin lower-boundary value
        if (lb > xd + GMARG) break;             // all further mins > x+G -> flag
        if (bc[bn]) {
          proven = ((double)kasc2f(bmn[bn]) - xd <= GMARG);
          break;
        }
      }
      // cap exhausted without proof -> flag (conservative over-include)
    }
    if (!proven) {
      u32 s = atomicAdd(&candCnt[arr], 1u);
      if (s < CAP) candVal[arr * CAP + s] = x;
    }
  }
}

// ---------------- per-block masked count/sum for each candidate threshold ----------------
// count_j = #{x > v_j}, sum_j = sum{x > v_j}; deterministic (fixed shuffle tree).
__global__ __launch_bounds__(256) void k_psum(const float* in0, const float* in1,
                                              const u32* candCnt, const float* candVal,
                                              u32* pCnt, double* pSum) {
  int arr = blockIdx.y, b = blockIdx.x, t = threadIdx.x;
  int lane = t & 63, w = t >> 6;
  __shared__ float lv[2048];
  const float* p = arr ? in1 : in0;
  ((float4*)lv)[t] = ((const float4*)(p + b * 2048))[t];
  ((float4*)lv)[t + 256] = ((const float4*)(p + b * 2048))[t + 256];
  __syncthreads();
  u32 cc = candCnt[arr];
  int cnt = (int)(cc < (u32)CAP ? cc : (u32)CAP);
  for (int j = w; j < cnt; j += 4) {
    float v = candVal[arr * CAP + j];
    int c = 0;
    double s = 0.0;
    for (int e = lane; e < 2048; e += 64) {
      float x = lv[e];
      if (x > v) { c++; s += (double)x; }
    }
#pragma unroll
    for (int o = 32; o > 0; o >>= 1) {
      c += __shfl_down(c, o);
      s += __shfl_down(s, o);
    }
    if (lane == 0) {
      pCnt[((size_t)(arr * NBLK + b)) * CAP + j] = (u32)c;
      pSum[((size_t)(arr * NBLK + b)) * CAP + j] = s;
    }
  }
}

// ---------------- reduce partials -> exact (p, C[p]) per candidate ----------------
__global__ __launch_bounds__(256) void k_cand(const u32* candCnt, const u32* pCnt,
                                              const double* pSum, int* cP, double* cC) {
  int arr = blockIdx.x, t = threadIdx.x;
  u32 cc = candCnt[arr];
  int cnt = (int)(cc < (u32)CAP ? cc : (u32)CAP);
  for (int j = t; j < cnt; j += 256) {
    long long c = 0;
    double s = 0.0;
    for (int b = 0; b < NBLK; b++) {  // fixed order -> deterministic
      c += (long long)pCnt[((size_t)(arr * NBLK + b)) * CAP + j];
      s += pSum[((size_t)(arr * NBLK + b)) * CAP + j];
    }
    double pd = (double)c;
    // C[p] = S_p/reg - (p*n - p(p-1)/2), exact in f64 (p*n < 2^53)
    cC[arr * CAP + j] = s / 0.1 - (pd * (double)N_ELEM - pd * (pd - 1.0) * 0.5);
    cP[arr * CAP + j] = (int)c;
  }
}

// ---------------- hull: sort by p, dedupe, monotone chain -> segments ----------------
__global__ __launch_bounds__(256) void k_hullk(const u32* candCnt, const float* candVal,
                                               const int* cP, const double* cC,
                                               float* segV, double* segS, int* segN) {
  int arr = blockIdx.x, t = threadIdx.x;
  u32 cc = candCnt[arr];
  int cnt = (int)(cc < (u32)CAP ? cc : (u32)CAP);
  __shared__ int sp[CAP];
  __shared__ double scv[CAP];
  __shared__ float svv[CAP];
  __shared__ int dp[CAP];
  __shared__ double dc[CAP];
  __shared__ float dv[CAP];
  __shared__ int ntop;
  for (int j = t; j < cnt; j += 256) {
    sp[j] = cP[arr * CAP + j];
    scv[j] = cC[arr * CAP + j];
    svv[j] = candVal[arr * CAP + j];
  }
  __syncthreads();
  // rank sort by (p, j); distinct values have distinct p, equal p => identical
  // records, so atomic-order nondeterminism cannot affect the sorted sequence
  for (int j = t; j < cnt; j += 256) {
    int pj = sp[j], rk = 0;
    for (int k = 0; k < cnt; k++) {
      int pk = sp[k];
      rk += (pk < pj) || (pk == pj && k < j);
    }
    dp[rk] = pj; dc[rk] = scv[j]; dv[rk] = svv[j];
  }
  __syncthreads();
  if (t == 0) {
    int top = 0, aX = 0, bX = 0, prevP = -1;
    double cA = 0.0, cB = 0.0;
    for (int k = 0; k < cnt; k++) {
      int i = dp[k];
      if (i == prevP) continue;  // dedupe identical diagram points
      prevP = i;
      double Ci = dc[k];
      float vi = dv[k];
      while (top >= 2) {
        double cr = (double)(bX - aX) * (Ci - cA) - (cB - cA) * (double)(i - aX);
        if (cr >= 0.0) {  // bX on/below chord aX->i : pop
          top--;
          bX = aX; cB = cA;
          if (top >= 2) { aX = dp[top - 2]; cA = dc[top - 2]; }
        } else break;
      }
      dp[top] = i; dc[top] = Ci; dv[top] = vi;  // write idx <= k: safe in-place
      aX = bX; cA = cB;
      bX = i;  cB = Ci;
      top++;
    }
    ntop = top;
  }
  __syncthreads();
  int top = ntop;
  for (int k = t; k < top - 1; k += 256) {
    segV[arr * CAP + k] = dv[k];  // left-vertex value of segment k (descending)
    segS[arr * CAP + k] = (dc[k + 1] - dc[k]) / (double)(dp[k + 1] - dp[k]);
  }
  if (t == 0) segN[arr] = top - 1;
}

// ---------------- fused rank + centered moments ----------------
// Element x in segment k iff v_k >= x > v_{k+1} (rank is a pure function of
// value: duplicates always pool). rank = x/reg - slope_k. Mean is analytic:
// permutahedron projection preserves coordinate sum -> mean = (N+1)/2.
__global__ __launch_bounds__(256) void k_rankmom(const float* in0, const float* in1,
                                                 const float* segV, const double* segS,
                                                 const int* segN, double* part) {
  int b = blockIdx.x, t = threadIdx.x;
  __shared__ float lv0[SEGCAP], lv1[SEGCAP];
  __shared__ double ls0[SEGCAP], ls1[SEGCAP];
  int n0 = segN[0], n1 = segN[1];
  bool f0 = (n0 <= SEGCAP), f1 = (n1 <= SEGCAP);
  if (f0) for (int k = t; k < n0; k += 256) { lv0[k] = segV[k]; ls0[k] = segS[k]; }
  if (f1) for (int k = t; k < n1; k += 256) { lv1[k] = segV[CAP + k]; ls1[k] = segS[CAP + k]; }
  __syncthreads();
  const double m = 0.5 * (double)(N_ELEM + 1);  // 65536.5
  double a0 = 0.0, a1 = 0.0, a2 = 0.0;
  const float4* q0 = (const float4*)(in0 + b * 1024);
  const float4* q1 = (const float4*)(in1 + b * 1024);
  float4 x4 = q0[t], y4 = q1[t];
  float xs[4] = {x4.x, x4.y, x4.z, x4.w};
  float ys[4] = {y4.x, y4.y, y4.z, y4.w};
#pragma unroll
  for (int e = 0; e < 4; e++) {
    float x = xs[e], y = ys[e];
    int k0 = 0, k1 = 0;
    if (f0) { for (int k = 1; k < n0; k++) if (x <= lv0[k]) k0 = k; }
    else    { for (int k = 1; k < n0; k++) if (x <= segV[k]) k0 = k; }
    if (f1) { for (int k = 1; k < n1; k++) if (y <= lv1[k]) k1 = k; }
    else    { for (int k = 1; k < n1; k++) if (y <= segV[CAP + k]) k1 = k; }
    double ra = (double)x / 0.1 - (f0 ? ls0[k0] : segS[k0]) - m;
    double rb = (double)y / 0.1 - (f1 ? ls1[k1] : segS[CAP + k1]) - m;
    a0 += ra * rb;
    a1 += ra * ra;
    a2 += rb * rb;
  }
  __shared__ double s0[256], s1[256], s2[256];
  s0[t] = a0; s1[t] = a1; s2[t] = a2;
  __syncthreads();
  for (int off = 128; off > 0; off >>= 1) {
    if (t < off) { s0[t] += s0[t + off]; s1[t] += s1[t + off]; s2[t] += s2[t + off]; }
    __syncthreads();
  }
  if (t == 0) {
    part[b] = s0[0];
    part[RM_BLK + b] = s1[0];
    part[2 * RM_BLK + b] = s2[0];
  }
}

__global__ __launch_bounds__(128) void k_final(const double* part, float* out) {
  int t = threadIdx.x;
  __shared__ double s0[128], s1[128], s2[128];
  s0[t] = part[t];
  s1[t] = part[RM_BLK + t];
  s2[t] = part[2 * RM_BLK + t];
  __syncthreads();
  for (int off = 64; off > 0; off >>= 1) {
    if (t < off) { s0[t] += s0[t + off]; s1[t] += s1[t + off]; s2[t] += s2[t + off]; }
    __syncthreads();
  }
  if (t == 0) out[0] = (float)(s0[0] / (sqrt(s1[0]) * sqrt(s2[0])));
}

// ---------------- host ----------------
extern "C" void kernel_launch(void* const* d_in, const int* in_sizes, int n_in,
                              void* d_out, int out_size, void* d_ws, size_t ws_size,
                              hipStream_t stream) {
  const float* in0 = (const float*)d_in[0];
  const float* in1 = (const float*)d_in[1];
  float* out = (float*)d_out;

  size_t off = 0;
  char* base = (char*)d_ws;
  auto alloc = [&](size_t bytes) -> char* {
    char* p = base + off;
    off += (bytes + 63) & ~(size_t)63;
    return p;
  };
  u32* binCnt  = (u32*)alloc(sizeof(u32) * 2 * NBIN);
  u32* binMinK = (u32*)alloc(sizeof(u32) * 2 * NBIN);
  u32* binMaxK = (u32*)alloc(sizeof(u32) * 2 * NBIN);
  u32* candCnt = (u32*)alloc(sizeof(u32) * 2);
  float* candVal = (float*)alloc(sizeof(float) * 2 * CAP);
  u32* pCnt    = (u32*)alloc(sizeof(u32) * 2 * NBLK * CAP);
  double* pSum = (double*)alloc(sizeof(double) * 2 * NBLK * CAP);
  int* cP      = (int*)alloc(sizeof(int) * 2 * CAP);
  double* cC   = (double*)alloc(sizeof(double) * 2 * CAP);
  float* segV  = (float*)alloc(sizeof(float) * 2 * CAP);
  double* segS = (double*)alloc(sizeof(double) * 2 * CAP);
  int* segN    = (int*)alloc(sizeof(int) * 2);
  double* part = (double*)alloc(sizeof(double) * 3 * RM_BLK);
  (void)ws_size; (void)in_sizes; (void)n_in; (void)out_size;

  k_zero<<<dim3(2 * NBIN / 256), dim3(256), 0, stream>>>(binCnt, binMinK, binMaxK, candCnt);
  k_hist<<<dim3(NBLK, 2), dim3(256), 0, stream>>>(in0, in1, binCnt, binMinK, binMaxK);
  k_flag<<<dim3(NBLK, 2), dim3(256), 0, stream>>>(in0, in1, binCnt, binMinK, binMaxK,
                                                  candCnt, candVal);
  k_psum<<<dim3(NBLK, 2), dim3(256), 0, stream>>>(in0, in1, candCnt, candVal, pCnt, pSum);
  k_cand<<<dim3(2), dim3(256), 0, stream>>>(candCnt, pCnt, pSum, cP, cC);
  k_hullk<<<dim3(2), dim3(256), 0, stream>>>(candCnt, candVal, cP, cC, segV, segS, segN);
  k_rankmom<<<dim3(RM_BLK), dim3(256), 0, stream>>>(in0, in1, segV, segS, segN, part);
  k_final<<<dim3(1), dim3(128), 0, stream>>>(part, out);
}

// Round 6
// 65.870 us; speedup vs baseline: 2.1686x; 2.1686x over previous
//
#include <hip/hip_runtime.h>
#include <math.h>

typedef unsigned int u32;
typedef unsigned long long u64;

#define N_ELEM 131072
#define NBIN 16384         // 14-bit key-space bins
#define BSH 18             // key >> 18 -> bin
#define CAP 4096           // candidate capacity per array (typ. ~25 used)
#define SEGCAP 2048        // LDS segment-table capacity in rankmom
#define SCAN_CAP 64        // max bins scanned upward in successor proof
#define GMARG 0.0999       // conservative gap margin (< 0.1*(1-1e-9))
#define NBLK 64            // data blocks per array (2048 elems each)
#define RM_BLK 128         // rankmom blocks

// ascending-sortable key: monotone bijection f32 -> u32
__device__ __forceinline__ u32 kasc(float x) {
  u32 u = __float_as_uint(x);
  return (u & 0x80000000u) ? ~u : (u | 0x80000000u);
}
__device__ __forceinline__ float kasc2f(u32 t) {
  return __uint_as_float((t & 0x80000000u) ? (t ^ 0x80000000u) : ~t);
}

// ---------------- init scratch (ws is poisoned, not re-poisoned between replays) ----
__global__ __launch_bounds__(256) void k_zero(u32* binMinK, u32* binMaxK, u32* candCnt) {
  int i = blockIdx.x * 256 + threadIdx.x;  // grid 128 -> 32768 = 2*NBIN
  binMinK[i] = 0xFFFFFFFFu;
  binMaxK[i] = 0u;
  if (i < 2) candCnt[i] = 0u;
}

// ---------------- exact per-bin min/max keys (LDS-staged; bin nonempty <=> min!=~0) ----
__global__ __launch_bounds__(256) void k_hist(const float* in0, const float* in1,
                                              u32* binMinK, u32* binMaxK) {
  int arr = blockIdx.y, b = blockIdx.x, t = threadIdx.x;
  __shared__ u32 lmn[NBIN];  // 64 KB
  __shared__ u32 lmx[NBIN];  // 64 KB
  for (int k = t; k < NBIN; k += 256) { lmn[k] = 0xFFFFFFFFu; lmx[k] = 0u; }
  __syncthreads();
  const float* p = arr ? in1 : in0;
  const float4* p4 = (const float4*)(p + b * 2048);
  float4 va = p4[t], vb = p4[t + 256];
  float xs[8] = {va.x, va.y, va.z, va.w, vb.x, vb.y, vb.z, vb.w};
#pragma unroll
  for (int e = 0; e < 8; e++) {
    u32 k = kasc(xs[e]);
    u32 bin = k >> BSH;
    atomicMin(&lmn[bin], k);   // LDS atomics: order-independent -> deterministic
    atomicMax(&lmx[bin], k);
  }
  __syncthreads();
  u32* bmn = binMinK + arr * NBIN;
  u32* bmx = binMaxK + arr * NBIN;
  for (int k = t; k < NBIN; k += 256) {
    u32 mn = lmn[k];
    if (mn != 0xFFFFFFFFu) {   // flush nonempty bins only
      atomicMin(&bmn[k], mn);
      atomicMax(&bmx[k], lmx[k]);
    }
  }
}

// ---------------- candidate detection ----------------
// Flag x unless we can PROVE an element exists in (x, x+GMARG] (then the sorted
// gap above x's run is <= GMARG < reg -> x cannot be a hull vertex; rigorous
// necessary condition: vertex at p => y_{p-1} > y_p => gap > reg).
// Proof sources (exact values): own-bin maxKey, or first nonempty higher bin's
// minKey. Over-inclusion is safe: every flagged value v yields a valid diagram
// point (p,C[p]) with p = #{> v}; the exact f64 hull discards non-vertices.
__global__ __launch_bounds__(256) void k_flag(const float* in0, const float* in1,
                                              const u32* binMinK, const u32* binMaxK,
                                              u32* candCnt, float* candVal) {
  int arr = blockIdx.y, b = blockIdx.x, t = threadIdx.x;
  const float* p = arr ? in1 : in0;
  const u32* bmn = binMinK + arr * NBIN;
  const u32* bmx = binMaxK + arr * NBIN;
  if (b == 0 && t == 0) {  // right-endpoint sentinel: p = N (counts everything)
    u32 s = atomicAdd(&candCnt[arr], 1u);
    if (s < CAP) candVal[arr * CAP + s] = -INFINITY;
  }
  const float4* p4 = (const float4*)(p + b * 2048);
  float4 va = p4[t], vb = p4[t + 256];
  float xs[8] = {va.x, va.y, va.z, va.w, vb.x, vb.y, vb.z, vb.w};
  for (int e = 0; e < 8; e++) {
    float x = xs[e];
    double xd = (double)x;
    u32 k = kasc(x);
    u32 bn = k >> BSH;
    bool proven = false, decided = false;
    u32 mx = bmx[bn];
    if (mx > k) {  // someone strictly above me in my own bin (exact value known)
      proven = ((double)kasc2f(mx) - xd <= GMARG);
      decided = true;  // if not proven: higher bins are all > val(mx) > x+G -> flag
    }
    if (!decided) {
      for (int it = 0; it < SCAN_CAP; it++) {
        bn++;
        if (bn >= NBIN) break;  // nothing above -> flag (this is the max elem, p=0)
        double lb = (double)kasc2f(bn << BSH);  // bin lower-boundary value
        if (lb > xd + GMARG) break;             // all further mins > x+G -> flag
        u32 mn = bmn[bn];
        if (mn != 0xFFFFFFFFu) {
          proven = ((double)kasc2f(mn) - xd <= GMARG);
          break;
        }
      }
      // cap exhausted without proof -> flag (conservative over-include)
    }
    if (!proven) {
      u32 s = atomicAdd(&candCnt[arr], 1u);
      if (s < CAP) candVal[arr * CAP + s] = x;
    }
  }
}

// ---------------- per-block masked count/sum for each candidate threshold ----------------
// count_j = #{x > v_j}, sum_j = sum{x > v_j}; deterministic (fixed shuffle tree).
__global__ __launch_bounds__(256) void k_psum(const float* in0, const float* in1,
                                              const u32* candCnt, const float* candVal,
                                              u32* pCnt, double* pSum) {
  int arr = blockIdx.y, b = blockIdx.x, t = threadIdx.x;
  int lane = t & 63, w = t >> 6;
  __shared__ float lv[2048];
  const float* p = arr ? in1 : in0;
  ((float4*)lv)[t] = ((const float4*)(p + b * 2048))[t];
  ((float4*)lv)[t + 256] = ((const float4*)(p + b * 2048))[t + 256];
  __syncthreads();
  u32 cc = candCnt[arr];
  int cnt = (int)(cc < (u32)CAP ? cc : (u32)CAP);
  for (int j = w; j < cnt; j += 4) {
    float v = candVal[arr * CAP + j];
    int c = 0;
    double s = 0.0;
    for (int e = lane; e < 2048; e += 64) {
      float x = lv[e];
      if (x > v) { c++; s += (double)x; }
    }
#pragma unroll
    for (int o = 32; o > 0; o >>= 1) {
      c += __shfl_down(c, o);
      s += __shfl_down(s, o);
    }
    if (lane == 0) {
      pCnt[((size_t)(arr * NBLK + b)) * CAP + j] = (u32)c;
      pSum[((size_t)(arr * NBLK + b)) * CAP + j] = s;
    }
  }
}

// ---------------- hull: reduce partials -> (p, C[p]); sort by p; monotone chain ----
__global__ __launch_bounds__(256) void k_hullk(const u32* candCnt, const float* candVal,
                                               const u32* pCnt, const double* pSum,
                                               float* segV, double* segS, int* segN) {
  int arr = blockIdx.x, t = threadIdx.x;
  u32 cc = candCnt[arr];
  int cnt = (int)(cc < (u32)CAP ? cc : (u32)CAP);
  __shared__ int sp[CAP];
  __shared__ double scv[CAP];
  __shared__ float svv[CAP];
  __shared__ int dp[CAP];
  __shared__ double dc[CAP];
  __shared__ float dv[CAP];
  __shared__ int ntop;
  // fused k_cand: exact (p, C[p]) per candidate, fixed-order 64-partial reduce
  for (int j = t; j < cnt; j += 256) {
    long long c = 0;
    double s = 0.0;
    for (int b = 0; b < NBLK; b++) {
      c += (long long)pCnt[((size_t)(arr * NBLK + b)) * CAP + j];
      s += pSum[((size_t)(arr * NBLK + b)) * CAP + j];
    }
    double pd = (double)c;
    // C[p] = S_p/reg - (p*n - p(p-1)/2), exact in f64 (p*n < 2^53)
    sp[j] = (int)c;
    scv[j] = s / 0.1 - (pd * (double)N_ELEM - pd * (pd - 1.0) * 0.5);
    svv[j] = candVal[arr * CAP + j];
  }
  __syncthreads();
  // rank sort by (p, j); distinct values have distinct p, equal p => identical
  // records, so atomic-order nondeterminism cannot affect the sorted sequence
  for (int j = t; j < cnt; j += 256) {
    int pj = sp[j], rk = 0;
    for (int k = 0; k < cnt; k++) {
      int pk = sp[k];
      rk += (pk < pj) || (pk == pj && k < j);
    }
    dp[rk] = pj; dc[rk] = scv[j]; dv[rk] = svv[j];
  }
  __syncthreads();
  if (t == 0) {
    int top = 0, aX = 0, bX = 0, prevP = -1;
    double cA = 0.0, cB = 0.0;
    for (int k = 0; k < cnt; k++) {
      int i = dp[k];
      if (i == prevP) continue;  // dedupe identical diagram points
      prevP = i;
      double Ci = dc[k];
      float vi = dv[k];
      while (top >= 2) {
        double cr = (double)(bX - aX) * (Ci - cA) - (cB - cA) * (double)(i - aX);
        if (cr >= 0.0) {  // bX on/below chord aX->i : pop
          top--;
          bX = aX; cB = cA;
          if (top >= 2) { aX = dp[top - 2]; cA = dc[top - 2]; }
        } else break;
      }
      dp[top] = i; dc[top] = Ci; dv[top] = vi;  // write idx <= k: safe in-place
      aX = bX; cA = cB;
      bX = i;  cB = Ci;
      top++;
    }
    ntop = top;
  }
  __syncthreads();
  int top = ntop;
  for (int k = t; k < top - 1; k += 256) {
    segV[arr * CAP + k] = dv[k];  // left-vertex value of segment k (descending)
    segS[arr * CAP + k] = (dc[k + 1] - dc[k]) / (double)(dp[k + 1] - dp[k]);
  }
  if (t == 0) segN[arr] = top - 1;
}

// ---------------- fused rank + centered moments ----------------
// Element x in segment k iff v_k >= x > v_{k+1} (rank is a pure function of
// value: duplicates always pool). rank = x/reg - slope_k. Mean is analytic:
// permutahedron projection preserves coordinate sum -> mean = (N+1)/2.
__global__ __launch_bounds__(256) void k_rankmom(const float* in0, const float* in1,
                                                 const float* segV, const double* segS,
                                                 const int* segN, double* part) {
  int b = blockIdx.x, t = threadIdx.x;
  __shared__ float lv0[SEGCAP], lv1[SEGCAP];
  __shared__ double ls0[SEGCAP], ls1[SEGCAP];
  int n0 = segN[0], n1 = segN[1];
  bool f0 = (n0 <= SEGCAP), f1 = (n1 <= SEGCAP);
  if (f0) for (int k = t; k < n0; k += 256) { lv0[k] = segV[k]; ls0[k] = segS[k]; }
  if (f1) for (int k = t; k < n1; k += 256) { lv1[k] = segV[CAP + k]; ls1[k] = segS[CAP + k]; }
  __syncthreads();
  const double m = 0.5 * (double)(N_ELEM + 1);  // 65536.5
  double a0 = 0.0, a1 = 0.0, a2 = 0.0;
  const float4* q0 = (const float4*)(in0 + b * 1024);
  const float4* q1 = (const float4*)(in1 + b * 1024);
  float4 x4 = q0[t], y4 = q1[t];
  float xs[4] = {x4.x, x4.y, x4.z, x4.w};
  float ys[4] = {y4.x, y4.y, y4.z, y4.w};
#pragma unroll
  for (int e = 0; e < 4; e++) {
    float x = xs[e], y = ys[e];
    int k0 = 0, k1 = 0;
    if (f0) { for (int k = 1; k < n0; k++) if (x <= lv0[k]) k0 = k; }
    else    { for (int k = 1; k < n0; k++) if (x <= segV[k]) k0 = k; }
    if (f1) { for (int k = 1; k < n1; k++) if (y <= lv1[k]) k1 = k; }
    else    { for (int k = 1; k < n1; k++) if (y <= segV[CAP + k]) k1 = k; }
    double ra = (double)x / 0.1 - (f0 ? ls0[k0] : segS[k0]) - m;
    double rb = (double)y / 0.1 - (f1 ? ls1[k1] : segS[CAP + k1]) - m;
    a0 += ra * rb;
    a1 += ra * ra;
    a2 += rb * rb;
  }
  __shared__ double s0[256], s1[256], s2[256];
  s0[t] = a0; s1[t] = a1; s2[t] = a2;
  __syncthreads();
  for (int off = 128; off > 0; off >>= 1) {
    if (t < off) { s0[t] += s0[t + off]; s1[t] += s1[t + off]; s2[t] += s2[t + off]; }
    __syncthreads();
  }
  if (t == 0) {
    part[b] = s0[0];
    part[RM_BLK + b] = s1[0];
    part[2 * RM_BLK + b] = s2[0];
  }
}

__global__ __launch_bounds__(128) void k_final(const double* part, float* out) {
  int t = threadIdx.x;
  __shared__ double s0[128], s1[128], s2[128];
  s0[t] = part[t];
  s1[t] = part[RM_BLK + t];
  s2[t] = part[2 * RM_BLK + t];
  __syncthreads();
  for (int off = 64; off > 0; off >>= 1) {
    if (t < off) { s0[t] += s0[t + off]; s1[t] += s1[t + off]; s2[t] += s2[t + off]; }
    __syncthreads();
  }
  if (t == 0) out[0] = (float)(s0[0] / (sqrt(s1[0]) * sqrt(s2[0])));
}

// ---------------- host ----------------
extern "C" void kernel_launch(void* const* d_in, const int* in_sizes, int n_in,
                              void* d_out, int out_size, void* d_ws, size_t ws_size,
                              hipStream_t stream) {
  const float* in0 = (const float*)d_in[0];
  const float* in1 = (const float*)d_in[1];
  float* out = (float*)d_out;

  size_t off = 0;
  char* base = (char*)d_ws;
  auto alloc = [&](size_t bytes) -> char* {
    char* p = base + off;
    off += (bytes + 63) & ~(size_t)63;
    return p;
  };
  u32* binMinK = (u32*)alloc(sizeof(u32) * 2 * NBIN);
  u32* binMaxK = (u32*)alloc(sizeof(u32) * 2 * NBIN);
  u32* candCnt = (u32*)alloc(sizeof(u32) * 2);
  float* candVal = (float*)alloc(sizeof(float) * 2 * CAP);
  u32* pCnt    = (u32*)alloc(sizeof(u32) * 2 * NBLK * CAP);
  double* pSum = (double*)alloc(sizeof(double) * 2 * NBLK * CAP);
  float* segV  = (float*)alloc(sizeof(float) * 2 * CAP);
  double* segS = (double*)alloc(sizeof(double) * 2 * CAP);
  int* segN    = (int*)alloc(sizeof(int) * 2);
  double* part = (double*)alloc(sizeof(double) * 3 * RM_BLK);
  (void)ws_size; (void)in_sizes; (void)n_in; (void)out_size;

  k_zero<<<dim3(2 * NBIN / 256), dim3(256), 0, stream>>>(binMinK, binMaxK, candCnt);
  k_hist<<<dim3(NBLK, 2), dim3(256), 0, stream>>>(in0, in1, binMinK, binMaxK);
  k_flag<<<dim3(NBLK, 2), dim3(256), 0, stream>>>(in0, in1, binMinK, binMaxK,
                                                  candCnt, candVal);
  k_psum<<<dim3(NBLK, 2), dim3(256), 0, stream>>>(in0, in1, candCnt, candVal, pCnt, pSum);
  k_hullk<<<dim3(2), dim3(256), 0, stream>>>(candCnt, candVal, pCnt, pSum, segV, segS, segN);
  k_rankmom<<<dim3(RM_BLK), dim3(256), 0, stream>>>(in0, in1, segV, segS, segN, part);
  k_final<<<dim3(1), dim3(128), 0, stream>>>(part, out);
}